// Round 13
// baseline (175.325 us; speedup 1.0000x reference)
//
#include <hip/hip_runtime.h>

#define B 8
#define P 2048
#define C 1024
#define NCHUNK 32
#define FEAT4 (B*P*C/4)   // 4194304 float4s of features
#define CEN4  (B*P*3/4)   // 12288 float4s of centers (and of cls_preds)

typedef unsigned long long u64;
typedef unsigned int u32;

// ---------------------------------------------------------------------------
// K1: full-GPU rank sort (R7, unchanged). Keys unique => rank is a bijection.
// ---------------------------------------------------------------------------
__global__ __launch_bounds__(512) void rank_kernel(
    const float* __restrict__ centers,
    const float* __restrict__ cls_preds,
    float4* __restrict__ scent,
    int* __restrict__ sidx)
{
    __shared__ u64 s_keys[P];       // 16 KB
    __shared__ u32 s_cnt[64][9];    // padded reduce buffer
    const int b = blockIdx.x >> 5, gi = blockIdx.x & 31;
    const int tid = threadIdx.x, wv = tid >> 6, lane = tid & 63;
    const float* clsb = cls_preds + (size_t)b * P * 3;
    const float* cenb = centers + (size_t)b * P * 3;

    for (int e = tid; e < P; e += 512) {
        float s0 = clsb[e*3], s1 = clsb[e*3+1], s2 = clsb[e*3+2];
        float sc = s0; int lb = 0;
        if (s1 > sc) { sc = s1; lb = 1; }
        if (s2 > sc) { sc = s2; lb = 2; }
        u32 ub = __float_as_uint(sc);
        u32 ord = (ub & 0x80000000u) ? ~ub : (ub | 0x80000000u);
        s_keys[e] = ((u64)(~ord) << 32) | (u32)((e << 2) | lb);
    }
    __syncthreads();

    const u64 myk = s_keys[(gi << 6) + lane];
    u32 c = 0;
    const int sbase = wv << 8;
    #pragma unroll 8
    for (int u = 0; u < 256; ++u)            // wave-uniform -> broadcast, free
        c += (s_keys[sbase + u] < myk) ? 1u : 0u;
    s_cnt[lane][wv] = c;
    __syncthreads();

    if (wv == 0) {
        u32 rank = 0;
        #pragma unroll
        for (int s = 0; s < 8; ++s) rank += s_cnt[lane][s];
        u32 lo = (u32)myk;
        int orig = (int)(lo >> 2);
        float4 cc;
        cc.x = cenb[orig*3]; cc.y = cenb[orig*3+1]; cc.z = cenb[orig*3+2];
        cc.w = __int_as_float((int)(lo & 3));
        scent[(size_t)b * P + rank] = cc;
        sidx[(size_t)b * P + rank] = (int)lo;
    }
}

// ---------------------------------------------------------------------------
// K2: suppression rows, triangle-trimmed (scan only consumes matT[w][i] with
// w >= 2*(i/64); sub-diagonal words left as poison -- harmless, see K3 proof).
// ---------------------------------------------------------------------------
__global__ __launch_bounds__(512) void matrix_kernel(
    const float4* __restrict__ scent,
    const float* __restrict__ class_radius,
    u32* __restrict__ matT)
{
    __shared__ float4 s_cent[P];   // 32 KB
    const int b = blockIdx.x >> 5, gi = blockIdx.x & 31;
    const int tid = threadIdx.x, wv = tid >> 6, lane = tid & 63;

    const float4 cj = scent[(size_t)b * P + (gi << 6) + lane];  // coalesced
    const int labj = __float_as_int(cj.w);
    const float r = class_radius[labj];
    const float r2 = r * r;
    const int wmin = gi << 1;

    for (int i = tid; i < P; i += 512) s_cent[i] = scent[(size_t)b * P + i];
    __syncthreads();

    for (int w = wv; w < 64; w += 8) {
        if (w < wmin) continue;                       // dead sub-diagonal
        u32 acc = 0;
        #pragma unroll
        for (int u = 0; u < 32; ++u) {
            float4 ci = s_cent[(w << 5) + u];         // uniform -> broadcast
            float dx = cj.x - ci.x, dy = cj.y - ci.y, dz = cj.z - ci.z;
            bool sup = (__float_as_int(ci.w) == labj)
                       && (dx*dx + dy*dy + dz*dz < r2);
            acc |= ((u32)sup) << u;
        }
        matT[((size_t)b * 64 + w) * P + (gi << 6) + lane] = acc;  // coalesced
    }
}

// ---------------------------------------------------------------------------
// K3: greedy resolution -- register-resident tiles, barrier-transparent
// depth-3 prefetch (R11 structure), now at 320 THREADS / 5 WAVES: both
// per-chunk barriers sync 5 waves instead of 9 (barrier is the critical
// path at 1 block/CU), atomicOr fan-in per word drops 8->4 waves. Holder
// wave w (1..4), lane l holds words w'=l of 16 rows qb=16(w-1)..qb+15
// (4 x uint4 per slot = 64 B contiguous per lane -- same pattern as R11,
// wider). Register loads carry no vmcnt obligation at s_barrier; waited on
// only at use, 3 chunks after issue. Keep scatter in a cooperative tail so
// loop barriers fence LDS only.
// Garbage-word proof: word l of a chunk-c row is valid iff l >= 2c; garbage
// ORs land only in s_removed[l], l < 2c, last read at chunk l/2 < c --
// strictly before the write. Reads only ever see valid words.
// ---------------------------------------------------------------------------
__global__ __launch_bounds__(320) void scan_kernel(
    const u32* __restrict__ matT,
    const int* __restrict__ sidx,
    float* __restrict__ out_keep)
{
    __shared__ int s_sidx[P];
    __shared__ u32 s_removed[64];
    __shared__ u64 s_keepm[NCHUNK];
    const int b = blockIdx.x;
    const int tid = threadIdx.x, wv = tid >> 6, lane = tid & 63;
    const u32* mb = matT + (size_t)b * 64 * P;

    for (int i = tid; i < P; i += 320) s_sidx[i] = sidx[(size_t)b * P + i];
    if (tid < 64) s_removed[tid] = 0;

    uint4 V[4][4];                       // waves 1..4: [slot][j] tile regs
    u32 Ra[4], Rb[4];                    // wave 0: resolve-row slots (regs)
    const int qb = (wv - 1) << 4;        // wave's q-base (valid for wv>=1)

    #pragma unroll
    for (int c = 0; c < 3; ++c) {        // preload chunks 0..2
        if (wv >= 1) {
            const u32* p = mb + (size_t)lane * P + (c << 6) + qb;
            #pragma unroll
            for (int j = 0; j < 4; ++j)
                V[c][j] = *(const uint4*)(p + 4 * j);
        } else {
            Ra[c] = mb[(size_t)(2*c    ) * P + (c << 6) + lane];
            Rb[c] = mb[(size_t)(2*c + 1) * P + (c << 6) + lane];
        }
    }
    __syncthreads();

    #pragma unroll                        // FULL unroll: slot = g&3 constant
    for (int g = 0; g < NCHUNK; ++g) {
        const int slot = g & 3;
        if (g + 3 < NCHUNK) {             // issue prefetch for chunk g+3
            const int c = g + 3, ns = c & 3;
            if (wv >= 1) {
                const u32* p = mb + (size_t)lane * P + (c << 6) + qb;
                #pragma unroll
                for (int j = 0; j < 4; ++j)
                    V[ns][j] = *(const uint4*)(p + 4 * j);
            } else {
                Ra[ns] = mb[(size_t)(2*c    ) * P + (c << 6) + lane];
                Rb[ns] = mb[(size_t)(2*c + 1) * P + (c << 6) + lane];
            }
        }
        if (wv == 0) {
            u64 row = (u64)Ra[slot] | ((u64)Rb[slot] << 32);
            u64 rem = (u64)s_removed[2*g] | ((u64)s_removed[2*g + 1] << 32);
            u64 alive = ~rem;
            const u64 below = (1ull << lane) - 1ull;
            u64 keepm = 0;
            while (alive) {               // peeling: rounds = chain depth
                bool ok = ((alive >> lane) & 1ull) && ((row & alive & below) == 0ull);
                u64 newk = __ballot(ok);
                keepm |= newk;
                bool dead = (row & newk) != 0ull;
                u64 deadm = __ballot(dead);
                alive &= ~(newk | deadm);
            }
            if (lane == 0) s_keepm[g] = keepm;
        }
        __syncthreads();                  // fences LDS only: no vmcnt drain
        if (wv >= 1) {                    // distributed removed-update
            const u32 kb = (u32)(s_keepm[g] >> qb) & 0xffffu;
            u32 acc = 0;
            if (kb & 0x0001u) acc |= V[slot][0].x;
            if (kb & 0x0002u) acc |= V[slot][0].y;
            if (kb & 0x0004u) acc |= V[slot][0].z;
            if (kb & 0x0008u) acc |= V[slot][0].w;
            if (kb & 0x0010u) acc |= V[slot][1].x;
            if (kb & 0x0020u) acc |= V[slot][1].y;
            if (kb & 0x0040u) acc |= V[slot][1].z;
            if (kb & 0x0080u) acc |= V[slot][1].w;
            if (kb & 0x0100u) acc |= V[slot][2].x;
            if (kb & 0x0200u) acc |= V[slot][2].y;
            if (kb & 0x0400u) acc |= V[slot][2].z;
            if (kb & 0x0800u) acc |= V[slot][2].w;
            if (kb & 0x1000u) acc |= V[slot][3].x;
            if (kb & 0x2000u) acc |= V[slot][3].y;
            if (kb & 0x4000u) acc |= V[slot][3].z;
            if (kb & 0x8000u) acc |= V[slot][3].w;
            if (acc) atomicOr(&s_removed[lane], acc);
        }
        __syncthreads();
    }

    // tail: one cooperative keep-scatter (the loop's only global side effect)
    for (int pos = tid; pos < P; pos += 320) {
        u64 km = s_keepm[pos >> 6];
        int orig = s_sidx[pos] >> 2;
        out_keep[(size_t)b * P + orig] = ((km >> (pos & 63)) & 1ull) ? 1.0f : 0.0f;
    }
}

// ---------------------------------------------------------------------------
// K4: streaming mask (R12 form: suppressed rows are store-only, keep[row]
// block-uniform -> zero divergence; f*0 == -0 is absmax-safe).
// ---------------------------------------------------------------------------
__global__ __launch_bounds__(256) void mask_kernel(
    const float* __restrict__ centers,
    const float* __restrict__ features,
    const float* __restrict__ cls_preds,
    const float* __restrict__ keep,
    float* __restrict__ out_centers,
    float* __restrict__ out_feat,
    float* __restrict__ out_cls)
{
    const int idx = blockIdx.x * 256 + threadIdx.x;
    if (idx < FEAT4) {
        const int row = idx >> 8;                    // C/4 = 256 f4 per row
        const float m = keep[row];                   // block-uniform
        if (m != 0.0f) {
            float4 v = ((const float4*)features)[idx];
            v.x *= m; v.y *= m; v.z *= m; v.w *= m;
            ((float4*)out_feat)[idx] = v;
        } else {
            float4 z; z.x = 0.f; z.y = 0.f; z.z = 0.f; z.w = 0.f;
            ((float4*)out_feat)[idx] = z;            // store-only: no fetch
        }
    } else if (idx < FEAT4 + CEN4) {
        const int q = idx - FEAT4;
        float4 v = ((const float4*)centers)[q];
        const int e = q * 4;
        v.x *= keep[(e    ) / 3]; v.y *= keep[(e + 1) / 3];
        v.z *= keep[(e + 2) / 3]; v.w *= keep[(e + 3) / 3];
        ((float4*)out_centers)[q] = v;
    } else if (idx < FEAT4 + 2 * CEN4) {
        const int q = idx - FEAT4 - CEN4;
        float4 v = ((const float4*)cls_preds)[q];
        const int e = q * 4;
        v.x *= keep[(e    ) / 3]; v.y *= keep[(e + 1) / 3];
        v.z *= keep[(e + 2) / 3]; v.w *= keep[(e + 3) / 3];
        ((float4*)out_cls)[q] = v;
    }
}

extern "C" void kernel_launch(void* const* d_in, const int* in_sizes, int n_in,
                              void* d_out, int out_size, void* d_ws, size_t ws_size,
                              hipStream_t stream) {
    const float* centers      = (const float*)d_in[0];
    const float* features     = (const float*)d_in[1];
    const float* cls_preds    = (const float*)d_in[2];
    const float* class_radius = (const float*)d_in[3];

    float* out = (float*)d_out;
    float* out_centers = out;                                   // B*P*3
    float* out_feat    = out + (size_t)B * P * 3;               // B*P*C
    float* out_cls     = out_feat + (size_t)B * P * C;          // B*P*K
    float* out_keep    = out_cls + (size_t)B * P * 3;           // B*P

    // scratch inside out_feat (64 MB), fully rewritten by mask_kernel:
    //   matT  : 1,048,576 u32 (4 MB), layout matT[b][w][i]
    //   scent :    16,384 float4
    //   sidx  :    16,384 int
    u32*    matT  = (u32*)out_feat;
    float4* scent = (float4*)(out_feat + 1048576);
    int*    sidx  = (int*)(out_feat + 1048576 + 65536);

    hipLaunchKernelGGL(rank_kernel, dim3(B * 32), dim3(512), 0, stream,
                       centers, cls_preds, scent, sidx);
    hipLaunchKernelGGL(matrix_kernel, dim3(B * 32), dim3(512), 0, stream,
                       scent, class_radius, matT);
    hipLaunchKernelGGL(scan_kernel, dim3(B), dim3(320), 0, stream,
                       matT, sidx, out_keep);
    hipLaunchKernelGGL(mask_kernel, dim3((FEAT4 + 2 * CEN4 + 255) / 256), dim3(256),
                       0, stream,
                       centers, features, cls_preds, out_keep,
                       out_centers, out_feat, out_cls);
}